// Round 1
// baseline (159.420 us; speedup 1.0000x reference)
//
#include <hip/hip_runtime.h>
#include <cstdint>
#include <cstddef>

#define CCH 80
#define H 384
#define W 384
#define HW (H*W)            // 147456
#define CHW (CCH*HW)        // 11796480
#define XG (W/4)            // 96 groups of 4 cols
#define TY (H/8)            // 48 tile rows (8 rows each)
#define TILES_PER_HEAT (CCH*TY*XG)     // 368640
#define BLK_PER_HEAT (TILES_PER_HEAT/256)  // 1440
#define KTOP 100
#define NDET 1000
#define CANDMAX 4096
#define NBINS 1024

struct Ws {
  float chunkmax[2][BLK_PER_HEAT];   // max surviving sigmoid per block
  unsigned int cand_cnt[2];
  int thresh_bin[2];
  float cand_score[2][CANDMAX];
  int   cand_idx[2][CANDMAX];
  float c_sc[2][KTOP];
  float c_xf[2][KTOP];
  float c_yf[2][KTOP];
  float c_tag[2][KTOP];
  int   c_cls[2][KTOP];
};

__device__ __forceinline__ float sigf(float x) { return 1.0f / (1.0f + __expf(-x)); }
__device__ __forceinline__ int binf(float s) {
  int b = (int)(s * 1024.0f);
  return b < 0 ? 0 : (b > (NBINS-1) ? (NBINS-1) : b);
}
__device__ __forceinline__ float max3f(float a, float b, float c) { return fmaxf(a, fmaxf(b, c)); }

// Streaming 4x8 tile NMS on raw values (sigmoid is monotone, equality pattern
// preserved up to float-collision cases of negligible probability).
// Calls f(sigmoid, rel_idx_within_channel) for every surviving pixel.
template <typename F>
__device__ __forceinline__ void nms_tile(const float* __restrict__ ch, int x0, int y0, F f) {
  const float NEG = -__builtin_inff();
  float r[3][6];
  auto loadrow = [&](int yy, float* rr) {
    if ((unsigned)yy >= (unsigned)H) {
      #pragma unroll
      for (int q = 0; q < 6; ++q) rr[q] = NEG;
    } else {
      const float* row = ch + yy * W;
      const float4 v = *reinterpret_cast<const float4*>(row + x0);
      rr[1] = v.x; rr[2] = v.y; rr[3] = v.z; rr[4] = v.w;
      rr[0] = (x0 > 0)     ? row[x0 - 1] : NEG;
      rr[5] = (x0 + 4 < W) ? row[x0 + 4] : NEG;
    }
  };
  loadrow(y0 - 1, r[0]);
  loadrow(y0,     r[1]);
  #pragma unroll
  for (int dy = 0; dy < 8; ++dy) {
    float* ra = r[dy % 3];
    float* rb = r[(dy + 1) % 3];
    float* rc = r[(dy + 2) % 3];
    loadrow(y0 + dy + 1, rc);
    #pragma unroll
    for (int j = 0; j < 4; ++j) {
      float m = max3f(max3f(ra[j], ra[j+1], ra[j+2]),
                      max3f(rb[j], rb[j+1], rb[j+2]),
                      max3f(rc[j], rc[j+1], rc[j+2]));
      float cv = rb[j + 1];
      if (cv >= m) {           // center included in window -> local max (ties kept, matching h==m)
        f(sigf(cv), (y0 + dy) * W + x0 + j);
      }
    }
  }
}

__device__ __forceinline__ void tile_decode(int t, int& c, int& x0, int& y0) {
  c = t / (TY * XG);
  int rem = t - c * (TY * XG);
  int ty = rem / XG;
  int xg = rem - ty * XG;
  x0 = xg * 4;
  y0 = ty * 8;
}

__global__ __launch_bounds__(256) void nms_pass1(const float* __restrict__ tl,
                                                 const float* __restrict__ br,
                                                 Ws* __restrict__ ws) {
  int heat = blockIdx.y;
  const float* hsrc = heat ? br : tl;
  int t = blockIdx.x * 256 + threadIdx.x;
  int c, x0, y0;
  tile_decode(t, c, x0, y0);
  const float* ch = hsrc + c * HW;
  float lm = -__builtin_inff();
  nms_tile(ch, x0, y0, [&](float sg, int) { lm = fmaxf(lm, sg); });
  __shared__ float red[256];
  red[threadIdx.x] = lm;
  __syncthreads();
  for (int st = 128; st > 0; st >>= 1) {
    if (threadIdx.x < st) red[threadIdx.x] = fmaxf(red[threadIdx.x], red[threadIdx.x + st]);
    __syncthreads();
  }
  if (threadIdx.x == 0) ws->chunkmax[heat][blockIdx.x] = red[0];
}

__global__ __launch_bounds__(1024) void find_thresh(Ws* __restrict__ ws) {
  __shared__ unsigned int hist[NBINS];
  for (int heat = 0; heat < 2; ++heat) {
    for (int i = threadIdx.x; i < NBINS; i += 1024) hist[i] = 0;
    __syncthreads();
    for (int i = threadIdx.x; i < BLK_PER_HEAT; i += 1024) {
      float s = ws->chunkmax[heat][i];
      if (s > 0.0f) atomicAdd(&hist[binf(s)], 1u);
    }
    __syncthreads();
    if (threadIdx.x == 0) {
      unsigned int acc = 0; int T = 0;
      for (int b = NBINS - 1; b >= 0; --b) {
        acc += hist[b];
        if (acc >= KTOP) { T = b; break; }
      }
      ws->thresh_bin[heat] = T;
    }
    __syncthreads();
  }
}

__global__ __launch_bounds__(256) void nms_collect(const float* __restrict__ tl,
                                                   const float* __restrict__ br,
                                                   Ws* __restrict__ ws) {
  int heat = blockIdx.y;
  int T = ws->thresh_bin[heat];
  float cm = ws->chunkmax[heat][blockIdx.x];
  if (!(cm > 0.0f) || binf(cm) < T) return;   // whole-block uniform early exit
  const float* hsrc = heat ? br : tl;
  int t = blockIdx.x * 256 + threadIdx.x;
  int c, x0, y0;
  tile_decode(t, c, x0, y0);
  const float* ch = hsrc + c * HW;
  int cbase = c * HW;
  nms_tile(ch, x0, y0, [&](float sg, int rel) {
    if (binf(sg) >= T) {
      unsigned int pos = atomicAdd(&ws->cand_cnt[heat], 1u);
      if (pos < CANDMAX) {
        ws->cand_score[heat][pos] = sg;
        ws->cand_idx[heat][pos]   = cbase + rel;
      }
    }
  });
}

// Bitonic sort: descending score, ties -> ascending index (matches lax.top_k).
__device__ void bitonic_desc(float* s, int* ix, int n) {
  for (int k = 2; k <= n; k <<= 1) {
    for (int j = k >> 1; j > 0; j >>= 1) {
      for (int i = threadIdx.x; i < n; i += blockDim.x) {
        int p = i ^ j;
        if (p > i) {
          float sa = s[i], sb = s[p];
          int ia = ix[i], ib = ix[p];
          bool afirst = (sa > sb) || (sa == sb && ia < ib);
          bool up = ((i & k) == 0);
          if (up ? !afirst : afirst) { s[i] = sb; s[p] = sa; ix[i] = ib; ix[p] = ia; }
        }
      }
      __syncthreads();
    }
  }
}

__global__ __launch_bounds__(1024) void corner_topk(Ws* __restrict__ ws,
                                                    const float* __restrict__ tl_e,
                                                    const float* __restrict__ br_e,
                                                    const float* __restrict__ tl_o,
                                                    const float* __restrict__ br_o) {
  __shared__ float ss[CANDMAX];
  __shared__ int   si[CANDMAX];
  int heat = blockIdx.x;
  unsigned int n = ws->cand_cnt[heat];
  if (n > CANDMAX) n = CANDMAX;
  int sz = 128;
  while (sz < (int)n) sz <<= 1;
  for (int i = threadIdx.x; i < sz; i += 1024) {
    if (i < (int)n) { ss[i] = ws->cand_score[heat][i]; si[i] = ws->cand_idx[heat][i]; }
    else            { ss[i] = -__builtin_inff(); si[i] = 0x7fffffff; }
  }
  __syncthreads();
  bitonic_desc(ss, si, sz);
  if (threadIdx.x < KTOP) {
    float sc = ss[threadIdx.x];
    int idx = si[threadIdx.x];
    if ((unsigned)idx >= (unsigned)CHW) idx = 0;   // defensive (never taken in practice)
    int c = idx / HW;
    int rem = idx - c * HW;
    int y = rem / W;
    int x = rem - y * W;
    const float* e = heat ? br_e : tl_e;
    const float* o = heat ? br_o : tl_o;
    ws->c_sc[heat][threadIdx.x]  = sc;
    ws->c_cls[heat][threadIdx.x] = c;
    ws->c_tag[heat][threadIdx.x] = e[rem];
    ws->c_xf[heat][threadIdx.x]  = (float)x + o[rem];        // offs channel 0 = x
    ws->c_yf[heat][threadIdx.x]  = (float)y + o[HW + rem];   // offs channel 1 = y
  }
}

__global__ __launch_bounds__(1024) void final_dets(Ws* __restrict__ ws, float* __restrict__ out) {
  __shared__ float tsc[KTOP], txf[KTOP], tyf[KTOP], tta[KTOP];
  __shared__ int   tcl[KTOP];
  __shared__ float bsc[KTOP], bxf[KTOP], byf[KTOP], bta[KTOP];
  __shared__ int   bcl[KTOP];
  __shared__ float vs[CANDMAX];
  __shared__ int   vp[CANDMAX];
  __shared__ unsigned int vcnt;
  __shared__ unsigned int psum[1024];
  int tid = threadIdx.x;
  if (tid == 0) vcnt = 0;
  if (tid < KTOP) {
    tsc[tid] = ws->c_sc[0][tid]; txf[tid] = ws->c_xf[0][tid]; tyf[tid] = ws->c_yf[0][tid];
    tta[tid] = ws->c_tag[0][tid]; tcl[tid] = ws->c_cls[0][tid];
    bsc[tid] = ws->c_sc[1][tid]; bxf[tid] = ws->c_xf[1][tid]; byf[tid] = ws->c_yf[1][tid];
    bta[tid] = ws->c_tag[1][tid]; bcl[tid] = ws->c_cls[1][tid];
  }
  __syncthreads();

  // Each thread (tid<1000) owns pairs [tid*10, tid*10+10). Valid pairs are
  // collected (order fixed later by sort); valid-count feeds a prefix scan so
  // the -1.0 ties are emitted in ascending pair-index order, matching top_k.
  unsigned int cnt = 0;
  if (tid < 1000) {
    int p0 = tid * 10;
    for (int p = p0; p < p0 + 10; ++p) {
      int i = p / 100, j = p - 100 * (p / 100);
      bool inval = (fabsf(tta[i] - bta[j]) > 0.5f) || (tcl[i] != bcl[j]) ||
                   (txf[i] > bxf[j]) || (tyf[i] > byf[j]);
      if (!inval) {
        float sc = (tsc[i] + bsc[j]) * 0.5f;
        unsigned int pos = atomicAdd(&vcnt, 1u);
        if (pos < CANDMAX) { vs[pos] = sc; vp[pos] = p; }
        cnt++;
      }
    }
  }
  psum[tid] = cnt;
  __syncthreads();
  for (int d = 1; d < 1024; d <<= 1) {
    unsigned int v = (tid >= (unsigned)d) ? psum[tid - d] : 0u;
    __syncthreads();
    psum[tid] += v;
    __syncthreads();
  }
  unsigned int V = vcnt;
  unsigned int Vc = V > CANDMAX ? CANDMAX : V;

  int sz = 2;
  while (sz < (int)Vc) sz <<= 1;
  for (int i = tid; i < sz; i += 1024) {
    if (i >= (int)Vc) { vs[i] = -__builtin_inff(); vp[i] = 0x7fffffff; }
  }
  __syncthreads();
  bitonic_desc(vs, vp, sz);

  int nv = (int)(V < (unsigned)NDET ? V : (unsigned)NDET);
  if (nv > (int)Vc) nv = (int)Vc;
  for (int d = tid; d < nv; d += 1024) {
    int p = vp[d];
    int i = p / 100, j = p - 100 * (p / 100);
    float* o = out + d * 8;
    o[0] = txf[i]; o[1] = tyf[i]; o[2] = bxf[j]; o[3] = byf[j];
    o[4] = vs[d];  o[5] = tsc[i]; o[6] = bsc[j]; o[7] = (float)tcl[i];
  }

  if (tid < 1000) {
    unsigned int run = psum[tid] - cnt;   // valids before p0
    int p0 = tid * 10;
    for (int p = p0; p < p0 + 10; ++p) {
      int i = p / 100, j = p - 100 * (p / 100);
      bool inval = (fabsf(tta[i] - bta[j]) > 0.5f) || (tcl[i] != bcl[j]) ||
                   (txf[i] > bxf[j]) || (tyf[i] > byf[j]);
      if (!inval) { run++; continue; }
      unsigned int r = (unsigned int)p - run;   // rank among invalids (ascending p)
      unsigned int row = V + r;
      if (row < (unsigned)NDET) {
        float* o = out + row * 8;
        o[0] = txf[i]; o[1] = tyf[i]; o[2] = bxf[j]; o[3] = byf[j];
        o[4] = -1.0f;  o[5] = tsc[i]; o[6] = bsc[j]; o[7] = (float)tcl[i];
      }
    }
  }
}

extern "C" void kernel_launch(void* const* d_in, const int* in_sizes, int n_in,
                              void* d_out, int out_size, void* d_ws, size_t ws_size,
                              hipStream_t stream) {
  (void)in_sizes; (void)n_in; (void)out_size; (void)ws_size;
  const float* tl_heat = (const float*)d_in[0];
  const float* br_heat = (const float*)d_in[1];
  const float* tl_embd = (const float*)d_in[2];
  const float* br_embd = (const float*)d_in[3];
  const float* tl_offs = (const float*)d_in[4];
  const float* br_offs = (const float*)d_in[5];
  float* out = (float*)d_out;
  Ws* ws = (Ws*)d_ws;

  hipMemsetAsync(&ws->cand_cnt[0], 0, sizeof(unsigned int) * 2, stream);

  dim3 grid(BLK_PER_HEAT, 2);
  nms_pass1<<<grid, 256, 0, stream>>>(tl_heat, br_heat, ws);
  find_thresh<<<1, 1024, 0, stream>>>(ws);
  nms_collect<<<grid, 256, 0, stream>>>(tl_heat, br_heat, ws);
  corner_topk<<<2, 1024, 0, stream>>>(ws, tl_embd, br_embd, tl_offs, br_offs);
  final_dets<<<1, 1024, 0, stream>>>(ws, out);
}